// Round 8
// baseline (923.434 us; speedup 1.0000x reference)
//
#include <hip/hip_runtime.h>

#define B_    256
#define T_    2048
#define F_    37
#define TF    111   // 3F
#define U_    32
#define TU    96    // 3U
#define D_    16

#define KP    128   // padded K for MFMA
#define XSTR  136   // LDS row stride in bf16 (272 B)
#define MTILE 128   // timesteps per tile
#define TPB   4     // tiles per block (xz kernel)

#define L2E 1.4426950408889634f

typedef __attribute__((ext_vector_type(8))) short short8;
typedef __attribute__((ext_vector_type(4))) float f32x4;
typedef __attribute__((ext_vector_type(2))) float f32x2;

__device__ __forceinline__ float fast_exp2(float x) {
    float r; asm("v_exp_f32 %0, %1" : "=v"(r) : "v"(x)); return r;
}
__device__ __forceinline__ float fast_rcp(float x) {
    float r; asm("v_rcp_f32 %0, %1" : "=v"(r) : "v"(x)); return r;
}
__device__ __forceinline__ float sigmoid_fast(float x) {
    return fast_rcp(1.f + fast_exp2(-L2E * x));
}
__device__ __forceinline__ float rdlane(float v, int k) {
    return __uint_as_float(__builtin_amdgcn_readlane(__float_as_uint(v), k));
}
// every lane gets its cross-32 partner's value (hedge: partner = p0+p1-own)
__device__ __forceinline__ float swap_half(float x) {
    unsigned xi = __float_as_uint(x);
    auto p = __builtin_amdgcn_permlane32_swap(xi, xi, false, false);
    float f0 = __uint_as_float(p[0]);
    float f1 = __uint_as_float(p[1]);
    return (f0 + f1) - x;
}
__device__ __forceinline__ float bf2f(unsigned short u) {
    return __uint_as_float(((unsigned)u) << 16);
}
__device__ __forceinline__ unsigned short f2bf_rne(float x) {
    unsigned u = __float_as_uint(x);
    return (unsigned short)((u + 0x7FFFu + ((u >> 16) & 1u)) >> 16);
}
__device__ __forceinline__ unsigned pk_bf16(float a, float b) {
    unsigned u;
    asm("v_cvt_pk_bf16_f32 %0, %1, %2" : "=v"(u) : "v"(a), "v"(b));
    return u;
}

// packed f32 math: d = (s0.lo*s1.lo[+d.lo], s0.hi*s1.hi[+d.hi])
#define PKMUL(d, hs, w) \
    asm("v_pk_mul_f32 %0, %1, %2" : "=v"(d) : "s"(hs), "v"(w))
#define PKFMA(d, hs, w) \
    asm("v_pk_fma_f32 %0, %1, %2, %0" : "+v"(d) : "s"(hs), "v"(w))
#define PKADD(d, a, b) \
    asm("v_pk_add_f32 %0, %1, %2" : "=v"(d) : "v"(a), "v"(b))

#define SCHED_FENCE() __builtin_amdgcn_sched_barrier(0)

// ============================================================================
// Kernel 1: xz[b][t][0:96] = x[b,t,:] @ K + b_in (bf16 out), via MFMA.
// Tiles with t0 >= lengths[b] are skipped (validated rounds 2-7).
// ============================================================================
__global__ __launch_bounds__(256, 2) void gru_xz4_kernel(
    const float* __restrict__ dt,
    const float* __restrict__ values,
    const int*   __restrict__ meas,
    const float* __restrict__ kern,
    const float* __restrict__ bias,
    const int*   __restrict__ lengths,
    unsigned short* __restrict__ xz)
{
    __shared__ unsigned short sX[MTILE][XSTR];   // 34816 B
    __shared__ unsigned short sKT[TU][XSTR];     // 26112 B

    const int tid  = threadIdx.x;
    const int wave = tid >> 6;
    const int lane = tid & 63;
    const int lr   = lane & 15;          // A-row / B-col / D-col
    const int lk   = (lane >> 4) * 8;    // k offset within frag

    for (int idx = tid; idx < TU * (KP / 2); idx += 256) {
        int j = idx >> 6, kp = idx & 63;
        int k0 = 2 * kp, k1 = k0 + 1;
        float v0 = (k0 < TF) ? kern[k0 * TU + j] : 0.f;
        float v1 = (k1 < TF) ? kern[k1 * TU + j] : 0.f;
        *(unsigned*)&sKT[j][2 * kp] = pk_bf16(v0, v1);
    }
    __syncthreads();

    float bi[6];
    #pragma unroll
    for (int n = 0; n < 6; ++n) bi[n] = bias[n * 16 + lr];
    short8 bfr[6][4];
    #pragma unroll
    for (int n = 0; n < 6; ++n)
        #pragma unroll
        for (int kc = 0; kc < 4; ++kc)
            bfr[n][kc] = *(const short8*)&sKT[n * 16 + lr][kc * 32 + lk];

    for (int tt = 0; tt < TPB; ++tt) {
        const int tile = blockIdx.x * TPB + tt;
        const int b    = tile >> 4;
        const int t0   = (tile & 15) * MTILE;

        // uniform per block-iteration: all threads take the same path, so the
        // barrier pairing below stays consistent.
        if (t0 >= lengths[b]) continue;

        __syncthreads();

        for (int i = tid; i < MTILE * F_; i += 256) {
            int t = i / F_, f = i - t * F_;
            size_t g = ((size_t)b * T_ + (t0 + t)) * F_ + f;
            sX[t][f] = f2bf_rne(values[g]);
        }
        for (int i = tid; i < MTILE * F_; i += 256) {
            int t = i / F_, f = i - t * F_;
            size_t g = ((size_t)b * T_ + (t0 + t)) * F_ + f;
            sX[t][F_ + f] = meas[g] ? (unsigned short)0x3F80 : (unsigned short)0;
        }
        for (int i = tid; i < MTILE * F_; i += 256) {
            int t = i / F_, f = i - t * F_;
            size_t g = ((size_t)b * T_ + (t0 + t)) * F_ + f;
            sX[t][2 * F_ + f] = f2bf_rne(dt[g]);
        }
        for (int i = tid; i < MTILE * (KP - TF); i += 256) {
            int t = i / (KP - TF), p = i - t * (KP - TF);
            sX[t][TF + p] = 0;
        }
        __syncthreads();

        f32x4 acc[2][6];
        #pragma unroll
        for (int m = 0; m < 2; ++m)
            #pragma unroll
            for (int n = 0; n < 6; ++n) acc[m][n] = (f32x4){0.f, 0.f, 0.f, 0.f};

        #pragma unroll
        for (int kc = 0; kc < 4; ++kc) {
            short8 a0 = *(const short8*)&sX[wave * 32 + lr][kc * 32 + lk];
            short8 a1 = *(const short8*)&sX[wave * 32 + 16 + lr][kc * 32 + lk];
            #pragma unroll
            for (int n = 0; n < 6; ++n) {
                acc[0][n] = __builtin_amdgcn_mfma_f32_16x16x32_bf16(a0, bfr[n][kc], acc[0][n], 0, 0, 0);
                acc[1][n] = __builtin_amdgcn_mfma_f32_16x16x32_bf16(a1, bfr[n][kc], acc[1][n], 0, 0, 0);
            }
        }

        #pragma unroll
        for (int m = 0; m < 2; ++m) {
            #pragma unroll
            for (int r = 0; r < 4; ++r) {
                int t = t0 + wave * 32 + m * 16 + (lane >> 4) * 4 + r;
                unsigned short* dst = &xz[((size_t)b * T_ + t) * TU + lr];
                #pragma unroll
                for (int n = 0; n < 6; ++n)
                    dst[n * 16] = f2bf_rne(acc[m][n][r] + bi[n]);
            }
        }
    }
}

// ============================================================================
// Kernel 2: recurrence rec12. 128 blocks x 64 threads, 1 wave/CU.
// TWO sequences (b, b+128) interleaved in ONE wave: rec9's per-seq math,
// statements alternated so the SIMD always has an independent chain to issue
// while the other stalls (solo step = 535 cyc with only ~198 issued —
// ~335 cyc of operand-wait bubbles that a second in-wave stream can fill;
// r2/r3's cross-wave attempt was spill-confounded, this shares the 64-VGPR
// weight block between the seqs so there is no budget pressure).
// Finished sequences freeze for free: xApre = -1e30 => exp2 -> 0 => z = 1
// => hv preserved (<=1 ulp/step); loop runs to (max(len0,len1)+3)&~3,
// no remainder code, no sorting (wall = global max length regardless).
// ============================================================================
__global__ __attribute__((amdgpu_flat_work_group_size(64, 64),
                          amdgpu_waves_per_eu(1, 1)))
void gru_rec12_kernel(
    const unsigned short* __restrict__ xz,
    const float* __restrict__ demo,
    const int*   __restrict__ lengths,
    const float* __restrict__ W1,
    const float* __restrict__ b1,
    const float* __restrict__ W2,
    const float* __restrict__ b2,
    const float* __restrict__ rec_kernel,
    const float* __restrict__ bias,
    const float* __restrict__ Wo,
    const float* __restrict__ bo,
    float* __restrict__ out)
{
    const int bA  = blockIdx.x;
    const int bB  = blockIdx.x + (B_ / 2);
    const int l   = threadIdx.x;
    const int lc  = l & 31;
    const int len0 = lengths[bA];
    const int len1 = lengths[bB];
    const bool lower = (l < 32);

    // wpA[m] = -L2E * (RK[2m][l],    RK[2m+1][l])      (z col l<32 | r col)
    // wpB[m] = 2L2E * (RK[2m][64+lc],RK[2m+1][64+lc])  (h col)   — SHARED
    f32x2 wpA[16], wpB[16];
    #pragma unroll
    for (int m = 0; m < 16; ++m) {
        wpA[m] = (f32x2){-L2E * rec_kernel[(2 * m) * TU + l],
                         -L2E * rec_kernel[(2 * m + 1) * TU + l]};
        wpB[m] = (f32x2){2.f * L2E * rec_kernel[(2 * m) * TU + 64 + lc],
                         2.f * L2E * rec_kernel[(2 * m + 1) * TU + 64 + lc]};
    }
    float rbA = -L2E * bias[TU + l];
    float rbB = 2.f * L2E * bias[TU + 64 + lc];
    #pragma unroll
    for (int m = 0; m < 16; ++m) {
        asm volatile("" : "+v"(wpA[m]));
        asm volatile("" : "+v"(wpB[m]));
    }
    asm volatile("" : "+v"(rbA), "+v"(rbB));

    // h0 = relu(demo@W1+b1)@W2+b2, for both sequences
    auto h_init = [&](int bb) -> float {
        float av = 0.f;
        if (l < U_) {
            float a = b1[l];
            #pragma unroll
            for (int d = 0; d < D_; ++d) a += demo[bb * D_ + d] * W1[d * U_ + l];
            av = fmaxf(a, 0.f);
        }
        float h = b2[lc];
        #pragma unroll
        for (int k = 0; k < U_; ++k) h += rdlane(av, k) * W2[k * U_ + lc];
        return h;
    };
    float hv0 = h_init(bA);
    float hv1 = h_init(bB);

    const unsigned short* xp0 = xz + (size_t)bA * T_ * TU;
    const unsigned short* xp1 = xz + (size_t)bB * T_ * TU;
    unsigned short rA0[4], rB0[4], rA1[4], rB1[4];

    auto issue4 = [&](int tg, int len, const unsigned short* xp,
                      unsigned short* rA, unsigned short* rB) {
        #pragma unroll
        for (int i = 0; i < 4; ++i) {
            int t = tg + i; t = (t < len) ? t : (len - 1);
            rA[i] = xp[(size_t)t * TU + l];        // x_z (l<32) | x_r (l>=32)
            rB[i] = xp[(size_t)t * TU + 64 + lc];  // x_h
        }
    };

    // both sequences advance one step; statements alternated
    auto stepPair = [&](float pA0, float pB0, float pA1, float pB1) {
        f32x2 aA0[4], aA1s[4], aB0[4], aB1s[4];
        aA0[0]  = (f32x2){pA0, 0.f};  aA1s[0] = (f32x2){pA1, 0.f};
        aB0[0]  = (f32x2){rbB, 0.f};  aB1s[0] = (f32x2){rbB, 0.f};
        #pragma unroll
        for (int g = 0; g < 4; ++g) {
            f32x2 h0s[4], h1s[4];
            #pragma unroll
            for (int j = 0; j < 4; ++j) {
                int k = 8 * g + 2 * j;
                h0s[j] = (f32x2){rdlane(hv0, k), rdlane(hv0, k + 1)};
                h1s[j] = (f32x2){rdlane(hv1, k), rdlane(hv1, k + 1)};
            }
            #pragma unroll
            for (int j = 0; j < 4; ++j) {
                int m = 4 * g + j;
                if (g == 0 && j > 0) {
                    PKMUL(aA0[j], h0s[j], wpA[m]);  PKMUL(aA1s[j], h1s[j], wpA[m]);
                    PKMUL(aB0[j], h0s[j], wpB[m]);  PKMUL(aB1s[j], h1s[j], wpB[m]);
                } else {
                    PKFMA(aA0[j], h0s[j], wpA[m]);  PKFMA(aA1s[j], h1s[j], wpA[m]);
                    PKFMA(aB0[j], h0s[j], wpB[m]);  PKFMA(aB1s[j], h1s[j], wpB[m]);
                }
            }
            SCHED_FENCE();   // keep the group rotation => bounded SGPR pressure
        }
        f32x2 x01, x23, xT, y01, y23, yT;
        PKADD(x01, aA0[0], aA0[1]);   PKADD(y01, aA1s[0], aA1s[1]);
        PKADD(x23, aA0[2], aA0[3]);   PKADD(y23, aA1s[2], aA1s[3]);
        PKADD(xT, x01, x23);          PKADD(yT, y01, y23);
        float recA0 = xT.x + xT.y;    float recA1 = yT.x + yT.y;
        float eA0 = fast_exp2(recA0); float eA1 = fast_exp2(recA1);
        f32x2 u01, u23, uT, v01, v23, vT;
        PKADD(u01, aB0[0], aB0[1]);   PKADD(v01, aB1s[0], aB1s[1]);
        PKADD(u23, aB0[2], aB0[3]);   PKADD(v23, aB1s[2], aB1s[3]);
        PKADD(uT, u01, u23);          PKADD(vT, v01, v23);
        float recB0 = uT.x + uT.y;    float recB1 = vT.x + vT.y;
        float zr0 = fast_rcp(1.f + eA0);  float zr1 = fast_rcp(1.f + eA1);
        float sw0 = swap_half(zr0);       float sw1 = swap_half(zr1);
        float z0 = lower ? zr0 : sw0;     float z1 = lower ? zr1 : sw1;
        float r0 = lower ? sw0 : zr0;     float r1 = lower ? sw1 : zr1;
        float u20 = fmaf(r0, recB0, pB0); float u21 = fmaf(r1, recB1, pB1);
        float e20 = fast_exp2(u20);       float e21 = fast_exp2(u21);
        float R0 = fast_rcp(e20 + 1.f);   float R1 = fast_rcp(e21 + 1.f);
        float hh0 = fmaf(-2.f, R0, 1.f);  float hh1 = fmaf(-2.f, R1, 1.f);
        hv0 = fmaf(z0, hv0 - hh0, hh0);   hv1 = fmaf(z1, hv1 - hh1, hh1);
    };

    issue4(0, len0, xp0, rA0, rB0);
    issue4(0, len1, xp1, rA1, rB1);
    const int maxlen  = (len0 > len1) ? len0 : len1;
    const int maxlen4 = (maxlen + 3) & ~3;

    for (int tg = 0; tg < maxlen4; tg += 4) {
        float qA0[4], qB0[4], qA1[4], qB1[4];
        #pragma unroll
        for (int i = 0; i < 4; ++i) {
            // freeze: t >= len => xApre = -1e30 => z = 1 => hv carried
            qA0[i] = (tg + i < len0) ? fmaf(bf2f(rA0[i]), -L2E, rbA) : -1e30f;
            qB0[i] = bf2f(rB0[i]) * (2.f * L2E);
            qA1[i] = (tg + i < len1) ? fmaf(bf2f(rA1[i]), -L2E, rbA) : -1e30f;
            qB1[i] = bf2f(rB1[i]) * (2.f * L2E);
        }
        issue4(tg + 4, len0, xp0, rA0, rB0);   // prefetch next group
        issue4(tg + 4, len1, xp1, rA1, rB1);
        stepPair(qA0[0], qB0[0], qA1[0], qB1[0]);
        stepPair(qA0[1], qB0[1], qA1[1], qB1[1]);
        stepPair(qA0[2], qB0[2], qA1[2], qB1[2]);
        stepPair(qA0[3], qB0[3], qA1[3], qB1[3]);
    }

    float v0 = (l < U_) ? hv0 * Wo[l] : 0.f;
    v0 += __shfl_xor(v0, 16);
    v0 += __shfl_xor(v0, 8);
    v0 += __shfl_xor(v0, 4);
    v0 += __shfl_xor(v0, 2);
    v0 += __shfl_xor(v0, 1);
    if (l == 0) out[bA] = sigmoid_fast(v0 + bo[0]);

    float v1 = (l < U_) ? hv1 * Wo[l] : 0.f;
    v1 += __shfl_xor(v1, 16);
    v1 += __shfl_xor(v1, 8);
    v1 += __shfl_xor(v1, 4);
    v1 += __shfl_xor(v1, 2);
    v1 += __shfl_xor(v1, 1);
    if (l == 0) out[bB] = sigmoid_fast(v1 + bo[0]);
}

extern "C" void kernel_launch(void* const* d_in, const int* in_sizes, int n_in,
                              void* d_out, int out_size, void* d_ws, size_t ws_size,
                              hipStream_t stream) {
    const float* demo       = (const float*)d_in[0];
    const float* dt         = (const float*)d_in[1];
    const float* values     = (const float*)d_in[2];
    const int*   meas       = (const int*)  d_in[3];
    const int*   lengths    = (const int*)  d_in[4];
    const float* W1         = (const float*)d_in[5];
    const float* b1         = (const float*)d_in[6];
    const float* W2         = (const float*)d_in[7];
    const float* b2         = (const float*)d_in[8];
    const float* kern       = (const float*)d_in[9];
    const float* rec_kernel = (const float*)d_in[10];
    const float* bias       = (const float*)d_in[11];
    const float* Wo         = (const float*)d_in[12];
    const float* bo         = (const float*)d_in[13];
    float* out = (float*)d_out;

    unsigned short* xz = (unsigned short*)d_ws;   // 100.7 MB, fits (validated)
    hipLaunchKernelGGL(gru_xz4_kernel, dim3(B_ * (T_ / MTILE) / TPB), dim3(256), 0, stream,
                       dt, values, meas, kern, bias, lengths, xz);
    hipLaunchKernelGGL(gru_rec12_kernel, dim3(B_ / 2), dim3(64), 0, stream,
                       xz, demo, lengths, W1, b1, W2, b2,
                       rec_kernel, bias, Wo, bo, out);
}

// Round 9
// 503.519 us; speedup vs baseline: 1.8340x; 1.8340x over previous
//
#include <hip/hip_runtime.h>

#define B_    256
#define T_    2048
#define F_    37
#define TF    111   // 3F
#define U_    32
#define TU    96    // 3U
#define D_    16

#define KP    128   // padded K for MFMA
#define XSTR  136   // LDS row stride in bf16 (272 B)
#define MTILE 128   // timesteps per tile
#define TPB   4     // tiles per block (xz kernel)

#define L2E 1.4426950408889634f

typedef __attribute__((ext_vector_type(8))) short short8;
typedef __attribute__((ext_vector_type(4))) float f32x4;
typedef __attribute__((ext_vector_type(2))) float f32x2;

__device__ __forceinline__ float fast_exp2(float x) {
    float r; asm("v_exp_f32 %0, %1" : "=v"(r) : "v"(x)); return r;
}
__device__ __forceinline__ float fast_rcp(float x) {
    float r; asm("v_rcp_f32 %0, %1" : "=v"(r) : "v"(x)); return r;
}
__device__ __forceinline__ float sigmoid_fast(float x) {
    return fast_rcp(1.f + fast_exp2(-L2E * x));
}
__device__ __forceinline__ float rdlane(float v, int k) {
    return __uint_as_float(__builtin_amdgcn_readlane(__float_as_uint(v), k));
}
// every lane gets its cross-32 partner's value (hedge: partner = p0+p1-own)
__device__ __forceinline__ float swap_half(float x) {
    unsigned xi = __float_as_uint(x);
    auto p = __builtin_amdgcn_permlane32_swap(xi, xi, false, false);
    float f0 = __uint_as_float(p[0]);
    float f1 = __uint_as_float(p[1]);
    return (f0 + f1) - x;
}
__device__ __forceinline__ float bf2f(unsigned short u) {
    return __uint_as_float(((unsigned)u) << 16);
}
__device__ __forceinline__ unsigned short f2bf_rne(float x) {
    unsigned u = __float_as_uint(x);
    return (unsigned short)((u + 0x7FFFu + ((u >> 16) & 1u)) >> 16);
}
__device__ __forceinline__ unsigned pk_bf16(float a, float b) {
    unsigned u;
    asm("v_cvt_pk_bf16_f32 %0, %1, %2" : "=v"(u) : "v"(a), "v"(b));
    return u;
}

// packed f32 math, all-VGPR operands: d = (s0.lo*s1.lo[+d.lo], s0.hi*s1.hi[+d.hi])
#define PKMULV(d, hq, w) \
    asm("v_pk_mul_f32 %0, %1, %2" : "=v"(d) : "v"(hq), "v"(w))
#define PKFMAV(d, hq, w) \
    asm("v_pk_fma_f32 %0, %1, %2, %0" : "+v"(d) : "v"(hq), "v"(w))
#define PKADD(d, a, b) \
    asm("v_pk_add_f32 %0, %1, %2" : "=v"(d) : "v"(a), "v"(b))

#define SCHED_FENCE() __builtin_amdgcn_sched_barrier(0)
#define MEM_FENCE()   asm volatile("" ::: "memory")

// ============================================================================
// Kernel 1: xz[b][t][0:96] = x[b,t,:] @ K + b_in (bf16 out), via MFMA.
// Tiles with t0 >= lengths[b] are skipped (validated rounds 2-7).
// ============================================================================
__global__ __launch_bounds__(256, 2) void gru_xz4_kernel(
    const float* __restrict__ dt,
    const float* __restrict__ values,
    const int*   __restrict__ meas,
    const float* __restrict__ kern,
    const float* __restrict__ bias,
    const int*   __restrict__ lengths,
    unsigned short* __restrict__ xz)
{
    __shared__ unsigned short sX[MTILE][XSTR];   // 34816 B
    __shared__ unsigned short sKT[TU][XSTR];     // 26112 B

    const int tid  = threadIdx.x;
    const int wave = tid >> 6;
    const int lane = tid & 63;
    const int lr   = lane & 15;          // A-row / B-col / D-col
    const int lk   = (lane >> 4) * 8;    // k offset within frag

    for (int idx = tid; idx < TU * (KP / 2); idx += 256) {
        int j = idx >> 6, kp = idx & 63;
        int k0 = 2 * kp, k1 = k0 + 1;
        float v0 = (k0 < TF) ? kern[k0 * TU + j] : 0.f;
        float v1 = (k1 < TF) ? kern[k1 * TU + j] : 0.f;
        *(unsigned*)&sKT[j][2 * kp] = pk_bf16(v0, v1);
    }
    __syncthreads();

    float bi[6];
    #pragma unroll
    for (int n = 0; n < 6; ++n) bi[n] = bias[n * 16 + lr];
    short8 bfr[6][4];
    #pragma unroll
    for (int n = 0; n < 6; ++n)
        #pragma unroll
        for (int kc = 0; kc < 4; ++kc)
            bfr[n][kc] = *(const short8*)&sKT[n * 16 + lr][kc * 32 + lk];

    for (int tt = 0; tt < TPB; ++tt) {
        const int tile = blockIdx.x * TPB + tt;
        const int b    = tile >> 4;
        const int t0   = (tile & 15) * MTILE;

        // uniform per block-iteration: all threads take the same path, so the
        // barrier pairing below stays consistent.
        if (t0 >= lengths[b]) continue;

        __syncthreads();

        for (int i = tid; i < MTILE * F_; i += 256) {
            int t = i / F_, f = i - t * F_;
            size_t g = ((size_t)b * T_ + (t0 + t)) * F_ + f;
            sX[t][f] = f2bf_rne(values[g]);
        }
        for (int i = tid; i < MTILE * F_; i += 256) {
            int t = i / F_, f = i - t * F_;
            size_t g = ((size_t)b * T_ + (t0 + t)) * F_ + f;
            sX[t][F_ + f] = meas[g] ? (unsigned short)0x3F80 : (unsigned short)0;
        }
        for (int i = tid; i < MTILE * F_; i += 256) {
            int t = i / F_, f = i - t * F_;
            size_t g = ((size_t)b * T_ + (t0 + t)) * F_ + f;
            sX[t][2 * F_ + f] = f2bf_rne(dt[g]);
        }
        for (int i = tid; i < MTILE * (KP - TF); i += 256) {
            int t = i / (KP - TF), p = i - t * (KP - TF);
            sX[t][TF + p] = 0;
        }
        __syncthreads();

        f32x4 acc[2][6];
        #pragma unroll
        for (int m = 0; m < 2; ++m)
            #pragma unroll
            for (int n = 0; n < 6; ++n) acc[m][n] = (f32x4){0.f, 0.f, 0.f, 0.f};

        #pragma unroll
        for (int kc = 0; kc < 4; ++kc) {
            short8 a0 = *(const short8*)&sX[wave * 32 + lr][kc * 32 + lk];
            short8 a1 = *(const short8*)&sX[wave * 32 + 16 + lr][kc * 32 + lk];
            #pragma unroll
            for (int n = 0; n < 6; ++n) {
                acc[0][n] = __builtin_amdgcn_mfma_f32_16x16x32_bf16(a0, bfr[n][kc], acc[0][n], 0, 0, 0);
                acc[1][n] = __builtin_amdgcn_mfma_f32_16x16x32_bf16(a1, bfr[n][kc], acc[1][n], 0, 0, 0);
            }
        }

        #pragma unroll
        for (int m = 0; m < 2; ++m) {
            #pragma unroll
            for (int r = 0; r < 4; ++r) {
                int t = t0 + wave * 32 + m * 16 + (lane >> 4) * 4 + r;
                unsigned short* dst = &xz[((size_t)b * T_ + t) * TU + lr];
                #pragma unroll
                for (int n = 0; n < 6; ++n)
                    dst[n * 16] = f2bf_rne(acc[m][n][r] + bi[n]);
            }
        }
    }
}

// ============================================================================
// Kernel 2: recurrence rec13. 256 blocks x 64 threads (1 wave/CU).
// rec9 structure, but h is broadcast through the LDS crossbar instead of 32
// v_readlane ops: 1 ds_write_b32 (lane l -> sH[l]) + 8 uniform-address
// ds_read_b128 (hardware broadcast, conflict-free). Rationale: r3 + r8
// measured that a 2nd independent chain costs ~+430 cyc/step on the same
// SIMD — the solo step's ~335 un-issued cycles are crossbar OCCUPANCY from
// the 32 readlanes, not fillable bubbles. Moving the broadcast to the DS
// pipe removes that occupancy; pk-FMA h-operands become plain VGPR pairs.
// Same-wave DS ops execute in order -> write-then-read needs only a
// compiler memory fence (no barrier, no explicit waitcnt).
// Arithmetic identical to rec9 (f32) -> absmax unchanged.
// ============================================================================
__global__ __attribute__((amdgpu_flat_work_group_size(64, 64),
                          amdgpu_waves_per_eu(1, 1)))
void gru_rec13_kernel(
    const unsigned short* __restrict__ xz,
    const float* __restrict__ demo,
    const int*   __restrict__ lengths,
    const float* __restrict__ W1,
    const float* __restrict__ b1,
    const float* __restrict__ W2,
    const float* __restrict__ b2,
    const float* __restrict__ rec_kernel,
    const float* __restrict__ bias,
    const float* __restrict__ Wo,
    const float* __restrict__ bo,
    float* __restrict__ out)
{
    __shared__ float sH[64];

    const int b   = blockIdx.x;
    const int l   = threadIdx.x;
    const int lc  = l & 31;
    const int len = lengths[b];
    const bool lower = (l < 32);

    // wpA[m] = -L2E * (RK[2m][l],    RK[2m+1][l])      (z col l<32 | r col)
    // wpB[m] = 2L2E * (RK[2m][64+lc],RK[2m+1][64+lc])  (h col)
    f32x2 wpA[16], wpB[16];
    #pragma unroll
    for (int m = 0; m < 16; ++m) {
        wpA[m] = (f32x2){-L2E * rec_kernel[(2 * m) * TU + l],
                         -L2E * rec_kernel[(2 * m + 1) * TU + l]};
        wpB[m] = (f32x2){2.f * L2E * rec_kernel[(2 * m) * TU + 64 + lc],
                         2.f * L2E * rec_kernel[(2 * m + 1) * TU + 64 + lc]};
    }
    float rbA = -L2E * bias[TU + l];
    float rbB = 2.f * L2E * bias[TU + 64 + lc];
    #pragma unroll
    for (int m = 0; m < 16; ++m) {
        asm volatile("" : "+v"(wpA[m]));
        asm volatile("" : "+v"(wpB[m]));
    }
    asm volatile("" : "+v"(rbA), "+v"(rbB));

    // h0 = relu(demo@W1+b1)@W2+b2
    float av = 0.f;
    if (l < U_) {
        float a = b1[l];
        #pragma unroll
        for (int d = 0; d < D_; ++d) a += demo[b * D_ + d] * W1[d * U_ + l];
        av = fmaxf(a, 0.f);
    }
    float hv = b2[lc];
    #pragma unroll
    for (int k = 0; k < U_; ++k) hv += rdlane(av, k) * W2[k * U_ + lc];

    const unsigned short* xp = xz + (size_t)b * T_ * TU;
    unsigned short rA[4], rB[4];

    auto issue4 = [&](int tg) {
        #pragma unroll
        for (int i = 0; i < 4; ++i) {
            int t = tg + i; t = (t < len) ? t : (len - 1);
            rA[i] = xp[(size_t)t * TU + l];        // x_z (l<32) | x_r (l>=32)
            rB[i] = xp[(size_t)t * TU + 64 + lc];  // x_h
        }
    };

    typedef union { f32x4 q; f32x2 d[2]; } qd_u;

    // xApre = -L2E*xA + rbA ; xBpre = 2L2E*xB   (precomputed by caller)
    auto step = [&](float xApre, float xBpre) {
        // R1: broadcast h via LDS: write own slot, read back 32 h's as 8 b128
        sH[l] = hv;
        MEM_FENCE();                      // DS pipe is in-order per wave: RAW ok
        qd_u hq[8];
        #pragma unroll
        for (int q = 0; q < 8; ++q)
            hq[q].q = *(const f32x4*)&sH[4 * q];   // uniform addr = broadcast
        MEM_FENCE();
        SCHED_FENCE();
        // R2: A-path matvec -> recA -> exp   (hd[m] = hq[m>>1].d[m&1])
        f32x2 aA0 = (f32x2){xApre, 0.f}, aA1, aA2, aA3;
        PKFMAV(aA0, hq[0].d[0], wpA[0]);
        PKMULV(aA1, hq[0].d[1], wpA[1]);
        PKMULV(aA2, hq[1].d[0], wpA[2]);
        PKMULV(aA3, hq[1].d[1], wpA[3]);
        #pragma unroll
        for (int g = 1; g < 4; ++g) {
            PKFMAV(aA0, hq[2 * g].d[0],     wpA[4 * g]);
            PKFMAV(aA1, hq[2 * g].d[1],     wpA[4 * g + 1]);
            PKFMAV(aA2, hq[2 * g + 1].d[0], wpA[4 * g + 2]);
            PKFMAV(aA3, hq[2 * g + 1].d[1], wpA[4 * g + 3]);
        }
        f32x2 tA01, tA23, tA;
        PKADD(tA01, aA0, aA1); PKADD(tA23, aA2, aA3); PKADD(tA, tA01, tA23);
        float recA = tA.x + tA.y;
        float eA = fast_exp2(recA);
        SCHED_FENCE();
        // R3: B-path first half — fills exp latency
        f32x2 aB0 = (f32x2){rbB, 0.f}, aB1, aB2, aB3;
        PKFMAV(aB0, hq[0].d[0], wpB[0]);
        PKMULV(aB1, hq[0].d[1], wpB[1]);
        PKMULV(aB2, hq[1].d[0], wpB[2]);
        PKMULV(aB3, hq[1].d[1], wpB[3]);
        PKFMAV(aB0, hq[2].d[0], wpB[4]);
        PKFMAV(aB1, hq[2].d[1], wpB[5]);
        PKFMAV(aB2, hq[3].d[0], wpB[6]);
        PKFMAV(aB3, hq[3].d[1], wpB[7]);
        SCHED_FENCE();
        float zr = fast_rcp(1.f + eA);       // z (l<32) | r (l>=32)
        SCHED_FENCE();
        // R4: B-path second half + tree — fills rcp latency
        #pragma unroll
        for (int g = 2; g < 4; ++g) {
            PKFMAV(aB0, hq[2 * g].d[0],     wpB[4 * g]);
            PKFMAV(aB1, hq[2 * g].d[1],     wpB[4 * g + 1]);
            PKFMAV(aB2, hq[2 * g + 1].d[0], wpB[4 * g + 2]);
            PKFMAV(aB3, hq[2 * g + 1].d[1], wpB[4 * g + 3]);
        }
        f32x2 tB01, tB23, tB;
        PKADD(tB01, aB0, aB1); PKADD(tB23, aB2, aB3); PKADD(tB, tB01, tB23);
        float recB = tB.x + tB.y;
        SCHED_FENCE();
        // R5: tail
        float sw = swap_half(zr);            // partner's value
        float z  = lower ? zr : sw;
        float r  = lower ? sw : zr;
        float u2 = fmaf(r, recB, xBpre);     // 2L2E*(xB + r*rec_h)
        float e2 = fast_exp2(u2);
        float hh = fmaf(-2.f, fast_rcp(e2 + 1.f), 1.f);  // tanh
        hv = fmaf(z, hv - hh, hh);
    };

    issue4(0);
    const int full = len & ~3;
    for (int tg = 0; tg < full; tg += 4) {
        float pA0 = fmaf(bf2f(rA[0]), -L2E, rbA), pB0 = bf2f(rB[0]) * (2.f * L2E);
        float pA1 = fmaf(bf2f(rA[1]), -L2E, rbA), pB1 = bf2f(rB[1]) * (2.f * L2E);
        float pA2 = fmaf(bf2f(rA[2]), -L2E, rbA), pB2 = bf2f(rB[2]) * (2.f * L2E);
        float pA3 = fmaf(bf2f(rA[3]), -L2E, rbA), pB3 = bf2f(rB[3]) * (2.f * L2E);
        issue4(tg + 4);                        // prefetch next group
        step(pA0, pB0); step(pA1, pB1); step(pA2, pB2); step(pA3, pB3);
    }
    const int rem = len - full;
    if (rem > 0) step(fmaf(bf2f(rA[0]), -L2E, rbA), bf2f(rB[0]) * (2.f * L2E));
    if (rem > 1) step(fmaf(bf2f(rA[1]), -L2E, rbA), bf2f(rB[1]) * (2.f * L2E));
    if (rem > 2) step(fmaf(bf2f(rA[2]), -L2E, rbA), bf2f(rB[2]) * (2.f * L2E));

    float v = (l < U_) ? hv * Wo[l] : 0.f;
    v += __shfl_xor(v, 16);
    v += __shfl_xor(v, 8);
    v += __shfl_xor(v, 4);
    v += __shfl_xor(v, 2);
    v += __shfl_xor(v, 1);
    if (l == 0) out[b] = sigmoid_fast(v + bo[0]);
}

extern "C" void kernel_launch(void* const* d_in, const int* in_sizes, int n_in,
                              void* d_out, int out_size, void* d_ws, size_t ws_size,
                              hipStream_t stream) {
    const float* demo       = (const float*)d_in[0];
    const float* dt         = (const float*)d_in[1];
    const float* values     = (const float*)d_in[2];
    const int*   meas       = (const int*)  d_in[3];
    const int*   lengths    = (const int*)  d_in[4];
    const float* W1         = (const float*)d_in[5];
    const float* b1         = (const float*)d_in[6];
    const float* W2         = (const float*)d_in[7];
    const float* b2         = (const float*)d_in[8];
    const float* kern       = (const float*)d_in[9];
    const float* rec_kernel = (const float*)d_in[10];
    const float* bias       = (const float*)d_in[11];
    const float* Wo         = (const float*)d_in[12];
    const float* bo         = (const float*)d_in[13];
    float* out = (float*)d_out;

    unsigned short* xz = (unsigned short*)d_ws;   // 100.7 MB, fits (validated)
    hipLaunchKernelGGL(gru_xz4_kernel, dim3(B_ * (T_ / MTILE) / TPB), dim3(256), 0, stream,
                       dt, values, meas, kern, bias, lengths, xz);
    hipLaunchKernelGGL(gru_rec13_kernel, dim3(B_), dim3(64), 0, stream,
                       xz, demo, lengths, W1, b1, W2, b2,
                       rec_kernel, bias, Wo, bo, out);
}